// Round 14
// baseline (342.322 us; speedup 1.0000x reference)
//
#include <hip/hip_runtime.h>
#include <math.h>

#define BATCH 2
#define TSTEPS 8

typedef __attribute__((ext_vector_type(8))) short s16x8;   // 8 bf16
typedef __attribute__((ext_vector_type(4))) float f32x4;   // MFMA accum

__device__ __forceinline__ float hsig(float v){ return fminf(fmaxf(0.2f*v+0.5f,0.f),1.f); }
__device__ __forceinline__ ushort f2bf(float f){
    uint u = __builtin_bit_cast(uint, f);
    u = (u + 0x7FFFu + ((u >> 16) & 1u)) >> 16;
    return (ushort)u;
}
__device__ __forceinline__ uint pack2bf(float lo, float hi){
    return (uint)f2bf(lo) | ((uint)f2bf(hi) << 16);
}

// fragment-linear packing: dst[((t_n*KCH + c)*64 + lane)*8 + j]
template<int KCH, int Co>
__device__ __forceinline__ void packw(const float* __restrict__ W, ushort* __restrict__ dst, int d){
    int j = d & 7, lane = (d >> 3) & 63;
    int q = lane >> 4, l = lane & 15;
    int rest = d >> 9;
    int c = rest % KCH, t_n = rest / KCH;
    int k = c*32 + q*8 + j;
    int np = t_n*16 + l;
    int g = np & 3, co = np >> 2;
    dst[d] = f2bf(W[(size_t)k*(4*Co) + g*Co + co]);
}

// combined [Wx;Wh] packing: chunk c = tap*(CPX+CPH)+u; u<CPX -> Wx, else Wh
template<int CPX, int CPH, int CI, int CO>
__device__ __forceinline__ void packw_fused(const float* __restrict__ Wx, const float* __restrict__ Wh,
                                            ushort* __restrict__ dst, int d){
    constexpr int KCHc = 9*(CPX+CPH);
    int j = d & 7, lane = (d >> 3) & 63;
    int q = lane >> 4, l = lane & 15;
    int rest = d >> 9;
    int c = rest % KCHc, t_n = rest / KCHc;
    int tap = c/(CPX+CPH), u = c - tap*(CPX+CPH);
    int np = t_n*16 + l;
    int g = np & 3, co = np >> 2;
    float v;
    if (u < CPX) v = Wx[(size_t)(tap*CI + u*32 + q*8 + j)*(4*CO) + g*CO + co];
    else         v = Wh[(size_t)(tap*CO + (u-CPX)*32 + q*8 + j)*(4*CO) + g*CO + co];
    dst[d] = f2bf(v);
}

#define SZ_X    786432
#define SZ_WX1  884736
#define SZ_WH1  589824
#define SZ_WC2  442368
#define SZ_WC3  110592
#define SZ_PREP (SZ_X+SZ_WX1+SZ_WH1+SZ_WC2+SZ_WC3)

__global__ void prep_kernel(const float* __restrict__ x,
    const float* __restrict__ Wx1, const float* __restrict__ Wh1,
    const float* __restrict__ Wx2, const float* __restrict__ Wh2,
    const float* __restrict__ Wx3, const float* __restrict__ Wh3,
    ushort* __restrict__ xpad,
    ushort* __restrict__ Wxp1, ushort* __restrict__ Whp1,
    ushort* __restrict__ Wc2, ushort* __restrict__ Wc3)
{
    int i = blockIdx.x * 256 + threadIdx.x;
    if (i < SZ_X){
        int c = i % 192; int r = i / 192;
        int xx = r % 16; r /= 16; int yy = r % 16; int bt = r / 16;
        xpad[((size_t)bt*18*18 + (yy+1)*18 + (xx+1))*192 + c] = f2bf(x[i]);
        return;
    } i -= SZ_X;
    if (i < SZ_WX1){ packw<54,128>(Wx1, Wxp1, i); return; } i -= SZ_WX1;
    if (i < SZ_WH1){ packw<36,128>(Wh1, Whp1, i); return; } i -= SZ_WH1;
    if (i < SZ_WC2){ packw_fused<4,2,128,64>(Wx2, Wh2, Wc2, i); return; } i -= SZ_WC2;
    if (i < SZ_WC3){ packw_fused<2,1,64,32>(Wx3, Wh3, Wc3, i); }
}

// ---------------------------------------------------------------------------
// conv-x slice role (block1 only): one t-plane, 64 wgs. Zsc aliases patch.
// ---------------------------------------------------------------------------
__device__ __forceinline__ void conv1_role(char* smem, int lbid, int t,
    const ushort* __restrict__ Apad, const ushort* __restrict__ Wpk,
    const float* __restrict__ bias, float* __restrict__ Zx)
{
    constexpr int CI = 192, H = 16, W = 16;
    constexpr int PR = 4, PPX = 18, PCI = CI + 8;
    constexpr int KCH = 54, CPT = 6;
    constexpr int HW = H*W, HP = H+2, WP = W+2;
    constexpr int N4 = 512;
    constexpr int CH8 = CI/8;
    constexpr int TOT = PR*PPX*CH8;
    constexpr int TPB = HW/32;

    ushort* patch = (ushort*)smem;        // 28800 B
    float* Zsc = (float*)smem;            // aliased after barrier: 32*132*4

    const int tid = threadIdx.x, lane = tid & 63, wave = tid >> 6;
    const int quad = lane >> 4, l16 = lane & 15;
    const int lx = lbid % (2*TPB), ly = lbid / (2*TPB);
    const int b = lx / TPB;
    const int idx0 = (lx - b*TPB)*32;
    const int bt = b*TSTEPS + t;
    const int m0 = bt*HW + idx0;
    const int y0 = idx0 / W, x0 = 0;

    const ushort* gsrc = Apad + (size_t)bt*HP*WP*CI;
    for (int c = tid; c < TOT; c += 256){
        int pix = c / CH8, ch = c - pix*CH8;
        int prow = pix / PPX, ppx = pix - prow*PPX;
        *(uint4*)&patch[pix*PCI + ch*8] =
            *(const uint4*)(gsrc + ((size_t)(y0+prow)*WP + (x0+ppx))*CI + ch*8);
    }
    __syncthreads();

    const int tn0 = ly*8 + wave*2;
    const ushort* bptr0 = Wpk + ((size_t)tn0*KCH*64 + lane)*8;
    const ushort* bptr1 = Wpk + ((size_t)(tn0+1)*KCH*64 + lane)*8;

    int labase[2];
    #pragma unroll
    for (int s = 0; s < 2; ++s)
        labase[s] = (s*PPX + l16)*PCI + quad*8;

    f32x4 acc[2][2] = {};
    #pragma unroll
    for (int it = 0; it < KCH; ++it){
        const int tap = it / CPT, ci0 = (it - tap*CPT)*32;
        const int kh = tap/3, kw = tap - (tap/3)*3;
        const int off = (kh*PPX + kw)*PCI + ci0;
        s16x8 b0 = *(const s16x8*)(bptr0 + (size_t)it*512);
        s16x8 b1 = *(const s16x8*)(bptr1 + (size_t)it*512);
        s16x8 a0 = *(const s16x8*)&patch[labase[0] + off];
        s16x8 a1 = *(const s16x8*)&patch[labase[1] + off];
        acc[0][0] = __builtin_amdgcn_mfma_f32_16x16x32_bf16(a0, b0, acc[0][0], 0,0,0);
        acc[0][1] = __builtin_amdgcn_mfma_f32_16x16x32_bf16(a0, b1, acc[0][1], 0,0,0);
        acc[1][0] = __builtin_amdgcn_mfma_f32_16x16x32_bf16(a1, b0, acc[1][0], 0,0,0);
        acc[1][1] = __builtin_amdgcn_mfma_f32_16x16x32_bf16(a1, b1, acc[1][1], 0,0,0);
    }
    __syncthreads();   // all patch reads done before Zsc alias-write

    #pragma unroll
    for (int s = 0; s < 2; ++s){
        #pragma unroll
        for (int nt = 0; nt < 2; ++nt){
            const int col = ly*128 + wave*32 + nt*16 + l16;
            const float bv = bias[(col & 3)*128 + (col >> 2)];
            #pragma unroll
            for (int r = 0; r < 4; ++r)
                Zsc[(s*16 + quad*4 + r)*132 + wave*32 + nt*16 + l16] = acc[s][nt][r] + bv;
        }
    }
    __syncthreads();

    #pragma unroll
    for (int i = 0; i < 4; ++i){
        int c = i*256 + tid;
        int row = c >> 5, cc = (c & 31) << 2;
        *(float4*)&Zx[(size_t)(m0+row)*N4 + ly*128 + cc] = *(float4*)&Zsc[row*132 + cc];
    }
}

__global__ __launch_bounds__(256) void conv1_t0(
    const ushort* __restrict__ Apad, const ushort* __restrict__ Wpk,
    const float* __restrict__ bias, float* __restrict__ Zx)
{
    __shared__ __align__(16) char smem[28800];
    conv1_role(smem, blockIdx.x, 0, Apad, Wpk, bias, Zx);
}

// ---------------------------------------------------------------------------
// S1 role (block1): z = Zx1[t] + conv(h1), split-K over 4 waves. Zs aliases patch.
// ---------------------------------------------------------------------------
__device__ __forceinline__ void step1_role(char* smem, int lbid, int t, int first,
    const float* __restrict__ Zx, const ushort* __restrict__ Whpk,
    const ushort* __restrict__ hprev, ushort* __restrict__ hnew,
    float* __restrict__ cst,
    const float* __restrict__ gamma, const float* __restrict__ beta,
    const float* __restrict__ mmean, const float* __restrict__ mvar,
    ushort* __restrict__ outp)
{
    constexpr int CO = 128, H = 16, W = 16;
    constexpr int PR = 4, PPX = 18, PCO = CO + 8;
    constexpr int KCH = 36, CPT = 4, NJ = 9;
    constexpr int HW = H*W, HP = H+2, WP = W+2;
    constexpr int N4 = 512;
    constexpr int CH8 = CO/8;
    constexpr int TOT = PR*PPX*CH8;
    constexpr int PT = (BATCH*HW)/32;

    ushort* patch = (ushort*)smem;                 // 19584 B
    float* Zs = (float*)smem;                      // aliased: 18432 B
    float* Hs = (float*)(smem + 18432);            // 1024 B

    const int tid = threadIdx.x, lane = tid & 63, wave = tid >> 6;
    const int quad = lane >> 4, l16 = lane & 15;
    const int pxt = lbid % PT, colIdx = lbid / PT;
    const int m0 = pxt * 32;
    const int b2 = m0 / HW, rem = m0 - b2*HW;
    const int y0 = rem / W, x0 = 0;
    const int co0 = colIdx * 8;

    if (!first){
        const ushort* gsrc = hprev + (size_t)b2*HP*WP*CO;
        for (int c = tid; c < TOT; c += 256){
            int pix = c / CH8, ch = c - pix*CH8;
            int prow = pix / PPX, ppx = pix - prow*PPX;
            *(uint4*)&patch[pix*PCO + ch*8] =
                *(const uint4*)(gsrc + ((size_t)(y0+prow)*WP + (x0+ppx))*CO + ch*8);
        }
        __syncthreads();

        const int tn0 = colIdx*2;
        const ushort* bptr0 = Whpk + ((size_t)tn0*KCH*64 + lane)*8;
        const ushort* bptr1 = Whpk + ((size_t)(tn0+1)*KCH*64 + lane)*8;

        int labase[2];
        #pragma unroll
        for (int s = 0; s < 2; ++s)
            labase[s] = (s*PPX + l16)*PCO + quad*8;

        f32x4 acc[2][2] = {};
        #pragma unroll
        for (int j = 0; j < NJ; ++j){
            const int it = wave + 4*j;
            const int tap = it / CPT, ci0 = (it - tap*CPT)*32;
            const int kh = tap/3, kw = tap - (tap/3)*3;
            const int off = (kh*PPX + kw)*PCO + ci0;
            s16x8 b0 = *(const s16x8*)(bptr0 + (size_t)it*512);
            s16x8 b1 = *(const s16x8*)(bptr1 + (size_t)it*512);
            s16x8 a0 = *(const s16x8*)&patch[labase[0] + off];
            s16x8 a1 = *(const s16x8*)&patch[labase[1] + off];
            acc[0][0] = __builtin_amdgcn_mfma_f32_16x16x32_bf16(a0, b0, acc[0][0], 0,0,0);
            acc[0][1] = __builtin_amdgcn_mfma_f32_16x16x32_bf16(a0, b1, acc[0][1], 0,0,0);
            acc[1][0] = __builtin_amdgcn_mfma_f32_16x16x32_bf16(a1, b0, acc[1][0], 0,0,0);
            acc[1][1] = __builtin_amdgcn_mfma_f32_16x16x32_bf16(a1, b1, acc[1][1], 0,0,0);
        }
        __syncthreads();
        #pragma unroll
        for (int s = 0; s < 2; ++s)
            #pragma unroll
            for (int nt = 0; nt < 2; ++nt)
                #pragma unroll
                for (int r = 0; r < 4; ++r)
                    Zs[(wave*32 + s*16 + quad*4 + r)*36 + nt*16 + l16] = acc[s][nt][r];
        __syncthreads();
    }

    {
        const int px = tid >> 3, coin = tid & 7;
        const int m = m0 + px;
        const int rr = m - b2*HW;
        const int co = co0 + coin;
        const size_t zrow = (size_t)(b2*TSTEPS + t)*HW + rr;
        const float4 zx = *(const float4*)&Zx[zrow*N4 + colIdx*32 + coin*4];
        float zi = zx.x, zf = zx.y, zg = zx.z, zo = zx.w;
        if (!first){
            #pragma unroll
            for (int w = 0; w < 4; ++w){
                const float4 s = *(const float4*)&Zs[(w*32 + px)*36 + coin*4];
                zi += s.x; zf += s.y; zg += s.z; zo += s.w;
            }
        }
        const float iv = hsig(zi), fv = hsig(zf);
        const float gv = tanhf(zg), ov = hsig(zo);
        const float cold = first ? 0.f : cst[(size_t)m*CO + co];
        const float cn = fv*cold + iv*gv;
        cst[(size_t)m*CO + co] = cn;
        const float h = ov * tanhf(cn);
        const int y = rr / W, x = rr - (rr/W)*W;
        hnew[((size_t)b2*HP*WP + (y+1)*WP + (x+1))*CO + co] = f2bf(h);
        Hs[px*8 + coin] = (h - mmean[co])*rsqrtf(mvar[co]+1e-3f)*gamma[co] + beta[co];
    }
    __syncthreads();

    if (tid < 128){
        const int px = tid >> 2, q = tid & 3;
        const int ypos = q >> 1, xpos = q & 1;
        const int m = m0 + px;
        const int rr = m - b2*HW;
        const int y = rr / W, x = rr - (rr/W)*W;
        const float* hs = &Hs[px*8];
        uint4 v;
        v.x = pack2bf(hs[0], hs[1]); v.y = pack2bf(hs[2], hs[3]);
        v.z = pack2bf(hs[4], hs[5]); v.w = pack2bf(hs[6], hs[7]);
        const size_t opix = ((size_t)(b2*TSTEPS + t)*(2*H+2) + 2*y+1+ypos)*(size_t)(2*W+2) + 2*x+1+xpos;
        *(uint4*)&outp[opix*CO + co0] = v;
    }
}

// ---------------------------------------------------------------------------
// Fused step role (blocks 2/3): z = conv(x_t) + conv(h) + bias in ONE split-K
// loop over combined packed weights. Two LDS patches; Zs aliases them after
// a barrier. Epilogue: gates+BN+2x2 upsample.
// ---------------------------------------------------------------------------
template<int CI, int CO, int H, int W, int OUT_BF16>
__device__ __forceinline__ void stepf_role(char* smem, int lbid, int t, int first,
    const ushort* __restrict__ xsrc, const ushort* __restrict__ Wcp,
    const ushort* __restrict__ hprev, ushort* __restrict__ hnew,
    float* __restrict__ cst, const float* __restrict__ bias,
    const float* __restrict__ gamma, const float* __restrict__ beta,
    const float* __restrict__ mmean, const float* __restrict__ mvar,
    void* __restrict__ outp)
{
    constexpr int CPX = CI/32, CPH = CO/32, CPC = CPX+CPH;
    constexpr int KCH = 9*CPC;
    constexpr int NJ = (KCH + 3)/4;
    constexpr int PPX = 18;
    constexpr int PCIx = CI + 8, PCOh = CO + 8;
    constexpr int HW = H*W, HP = H+2, WP = W+2;
    constexpr int XT = W/16;
    constexpr int TPS = HW/32;
    constexpr int CHX = CI/8, CHH = CO/8;
    constexpr int TOTX = 72*CHX, TOTH = 72*CHH;

    ushort* xpatch = (ushort*)smem;
    ushort* hpatch = (ushort*)(smem + 4*PPX*PCIx*2);
    float* Zs = (float*)smem;                      // aliased after barrier
    float* Hs = (float*)(smem + 18432);

    const int tid = threadIdx.x, lane = tid & 63, wave = tid >> 6;
    const int quad = lane >> 4, l16 = lane & 15;
    const int pxt = lbid % (BATCH*TPS), colIdx = lbid / (BATCH*TPS);
    const int b2 = pxt / TPS, tau = pxt - b2*TPS;
    const int band = tau / XT, xt = tau - band*XT;
    const int y0 = band*2, x0 = xt*16;
    const int co0 = colIdx * 8;
    const int bt = b2*TSTEPS + t;

    {
        const ushort* gx = xsrc + (size_t)bt*HP*WP*CI;
        for (int c = tid; c < TOTX; c += 256){
            int pix = c / CHX, ch = c - pix*CHX;
            int prow = pix / PPX, ppx = pix - prow*PPX;
            *(uint4*)&xpatch[pix*PCIx + ch*8] =
                *(const uint4*)(gx + ((size_t)(y0+prow)*WP + (x0+ppx))*CI + ch*8);
        }
    }
    if (!first){
        const ushort* gh = hprev + (size_t)b2*HP*WP*CO;
        for (int c = tid; c < TOTH; c += 256){
            int pix = c / CHH, ch = c - pix*CHH;
            int prow = pix / PPX, ppx = pix - prow*PPX;
            *(uint4*)&hpatch[pix*PCOh + ch*8] =
                *(const uint4*)(gh + ((size_t)(y0+prow)*WP + (x0+ppx))*CO + ch*8);
        }
    }
    __syncthreads();

    const int tn0 = colIdx*2;
    const ushort* bptr0 = Wcp + ((size_t)tn0*KCH*64 + lane)*8;
    const ushort* bptr1 = Wcp + ((size_t)(tn0+1)*KCH*64 + lane)*8;

    int labX[2], labH[2];
    #pragma unroll
    for (int s = 0; s < 2; ++s){
        labX[s] = (s*PPX + l16)*PCIx + quad*8;
        labH[s] = (s*PPX + l16)*PCOh + quad*8;
    }

    f32x4 acc[2][2] = {};
    const int nj = (KCH - wave + 3) >> 2;
    #pragma unroll
    for (int j = 0; j < NJ; ++j){
        if (j < nj){
            const int it = wave + 4*j;
            const int tap = it / CPC, u = it - tap*CPC;
            if (!(first && u >= CPX)){
                const int kh = tap/3, kw = tap - (tap/3)*3;
                s16x8 b0 = *(const s16x8*)(bptr0 + (size_t)it*512);
                s16x8 b1 = *(const s16x8*)(bptr1 + (size_t)it*512);
                s16x8 a0, a1;
                if (u < CPX){
                    const int off = (kh*PPX + kw)*PCIx + u*32;
                    a0 = *(const s16x8*)&xpatch[labX[0] + off];
                    a1 = *(const s16x8*)&xpatch[labX[1] + off];
                } else {
                    const int off = (kh*PPX + kw)*PCOh + (u-CPX)*32;
                    a0 = *(const s16x8*)&hpatch[labH[0] + off];
                    a1 = *(const s16x8*)&hpatch[labH[1] + off];
                }
                acc[0][0] = __builtin_amdgcn_mfma_f32_16x16x32_bf16(a0, b0, acc[0][0], 0,0,0);
                acc[0][1] = __builtin_amdgcn_mfma_f32_16x16x32_bf16(a0, b1, acc[0][1], 0,0,0);
                acc[1][0] = __builtin_amdgcn_mfma_f32_16x16x32_bf16(a1, b0, acc[1][0], 0,0,0);
                acc[1][1] = __builtin_amdgcn_mfma_f32_16x16x32_bf16(a1, b1, acc[1][1], 0,0,0);
            }
        }
    }
    __syncthreads();   // patches no longer needed; Zs aliases them

    #pragma unroll
    for (int s = 0; s < 2; ++s)
        #pragma unroll
        for (int nt = 0; nt < 2; ++nt)
            #pragma unroll
            for (int r = 0; r < 4; ++r)
                Zs[(wave*32 + s*16 + quad*4 + r)*36 + nt*16 + l16] = acc[s][nt][r];
    __syncthreads();

    // gates: 32 px x 8 co
    {
        const int px = tid >> 3, coin = tid & 7;
        const int y = y0 + (px >> 4), x = x0 + (px & 15);
        const int m = b2*HW + y*W + x;
        const int co = co0 + coin;
        float zi = bias[co], zf = bias[CO + co], zg = bias[2*CO + co], zo = bias[3*CO + co];
        #pragma unroll
        for (int w = 0; w < 4; ++w){
            const float4 s = *(const float4*)&Zs[(w*32 + px)*36 + coin*4];
            zi += s.x; zf += s.y; zg += s.z; zo += s.w;
        }
        const float iv = hsig(zi), fv = hsig(zf);
        const float gv = tanhf(zg), ov = hsig(zo);
        const float cold = first ? 0.f : cst[(size_t)m*CO + co];
        const float cn = fv*cold + iv*gv;
        cst[(size_t)m*CO + co] = cn;
        const float h = ov * tanhf(cn);
        hnew[((size_t)b2*HP*WP + (y+1)*WP + (x+1))*CO + co] = f2bf(h);
        Hs[px*8 + coin] = (h - mmean[co])*rsqrtf(mvar[co]+1e-3f)*gamma[co] + beta[co];
    }
    __syncthreads();

    if (OUT_BF16){
        if (tid < 128){
            const int px = tid >> 2, q = tid & 3;
            const int ypos = q >> 1, xpos = q & 1;
            const int y = y0 + (px >> 4), x = x0 + (px & 15);
            const float* hs = &Hs[px*8];
            uint4 v;
            v.x = pack2bf(hs[0], hs[1]); v.y = pack2bf(hs[2], hs[3]);
            v.z = pack2bf(hs[4], hs[5]); v.w = pack2bf(hs[6], hs[7]);
            ushort* o = (ushort*)outp;
            const size_t opix = ((size_t)bt*(2*H+2) + 2*y+1+ypos)*(size_t)(2*W+2) + 2*x+1+xpos;
            *(uint4*)&o[opix*CO + co0] = v;
        }
    } else {
        const int px = tid >> 3, q = (tid >> 1) & 3, half = tid & 1;
        const int ypos = q >> 1, xpos = q & 1;
        const int y = y0 + (px >> 4), x = x0 + (px & 15);
        float4 v = *(const float4*)&Hs[px*8 + half*4];
        float* o = (float*)outp;
        const size_t opix = ((size_t)bt*(2*H) + 2*y+ypos)*(size_t)(2*W) + 2*x+xpos;
        *(float4*)&o[opix*CO + co0 + half*4] = v;
    }
}

// ---------------------------------------------------------------------------
// Mega pipeline launch: roles ordered S2f, S3f, S1, C1(next).
// ---------------------------------------------------------------------------
__global__ __launch_bounds__(256) void mega(
    int e1, int e2, int e3,
    int t_s2, int t_s3, int t_s1, int t_c1,
    int f1, int f2, int f3,
    const ushort* xpad, const ushort* Wxp1, const float* b1v, float* Zx1,
    const ushort* Whp1, const ushort* h1p, ushort* h1n, float* c1,
    const float* g1, const float* be1, const float* mm1, const float* mv1, ushort* x2pad,
    const ushort* Wc2, const float* b2v,
    const ushort* h2p, ushort* h2n, float* c2,
    const float* g2, const float* be2, const float* mm2, const float* mv2, ushort* x3pad,
    const ushort* Wc3, const float* b3v,
    const ushort* h3p, ushort* h3n, float* c3,
    const float* g3, const float* be3, const float* mm3, const float* mv3, float* outp)
{
    __shared__ __align__(16) char smem[29952];
    const int bid = blockIdx.x;
    if (bid < e1){
        stepf_role<128,64,32,32,1>(smem, bid, t_s2, f2, x2pad, Wc2, h2p, h2n, c2,
                                   b2v, g2, be2, mm2, mv2, x3pad);
        return;
    }
    if (bid < e2){
        stepf_role<64,32,64,64,0>(smem, bid - e1, t_s3, f3, x3pad, Wc3, h3p, h3n, c3,
                                  b3v, g3, be3, mm3, mv3, outp);
        return;
    }
    if (bid < e3){
        step1_role(smem, bid - e2, t_s1, f1, Zx1, Whp1, h1p, h1n, c1,
                   g1, be1, mm1, mv1, x2pad);
        return;
    }
    conv1_role(smem, bid - e3, t_c1, xpad, Wxp1, b1v, Zx1);
}

extern "C" void kernel_launch(void* const* d_in, const int* in_sizes, int n_in,
                              void* d_out, int out_size, void* d_ws, size_t ws_size,
                              hipStream_t stream) {
    const float* x   = (const float*)d_in[0];
    const float* Wx1 = (const float*)d_in[1];  const float* Wh1 = (const float*)d_in[2];
    const float* b1  = (const float*)d_in[3];  const float* g1  = (const float*)d_in[4];
    const float* be1 = (const float*)d_in[5];  const float* mm1 = (const float*)d_in[6];
    const float* mv1 = (const float*)d_in[7];
    const float* Wx2 = (const float*)d_in[8];  const float* Wh2 = (const float*)d_in[9];
    const float* b2  = (const float*)d_in[10]; const float* g2  = (const float*)d_in[11];
    const float* be2 = (const float*)d_in[12]; const float* mm2 = (const float*)d_in[13];
    const float* mv2 = (const float*)d_in[14];
    const float* Wx3 = (const float*)d_in[15]; const float* Wh3 = (const float*)d_in[16];
    const float* b3  = (const float*)d_in[17]; const float* g3  = (const float*)d_in[18];
    const float* be3 = (const float*)d_in[19]; const float* mm3 = (const float*)d_in[20];
    const float* mv3 = (const float*)d_in[21];

    char* ws = (char*)d_ws;
    size_t off = 0;
    auto alloc = [&](size_t bytes) { char* p = ws + off; off += (bytes + 255) & ~(size_t)255; return p; };

    float*  Zx1 = (float*)alloc(2097152ull * 4);   // 4096 x 512
    float*  c1  = (float*)alloc(65536ull * 4);
    float*  c2  = (float*)alloc(131072ull * 4);
    float*  c3  = (float*)alloc(262144ull * 4);

    // contiguous zero region (one memset): pads + h halo buffers
    char* zbase = alloc(17685504ull);
    ushort* xpad  = (ushort*)zbase;
    ushort* x2pad = xpad  + 995328;
    ushort* x3pad = x2pad + 2367488;
    ushort* h1A   = x3pad + 4460544;
    ushort* h1B   = h1A + 82944;
    ushort* h2A   = h1B + 82944;
    ushort* h2B   = h2A + 147968;
    ushort* h3A   = h2B + 147968;
    ushort* h3B   = h3A + 278784;

    ushort* Wxp1 = (ushort*)alloc(SZ_WX1 * 2ull);
    ushort* Whp1 = (ushort*)alloc(SZ_WH1 * 2ull);
    ushort* Wc2  = (ushort*)alloc(SZ_WC2 * 2ull);
    ushort* Wc3  = (ushort*)alloc(SZ_WC3 * 2ull);

    hipMemsetAsync(zbase, 0, 17685504ull, stream);

    prep_kernel<<<(SZ_PREP + 255) / 256, 256, 0, stream>>>(
        x, Wx1, Wh1, Wx2, Wh2, Wx3, Wh3,
        xpad, Wxp1, Whp1, Wc2, Wc3);

    conv1_t0<<<64, 256, 0, stream>>>(xpad, Wxp1, b1, Zx1);

    // pipeline: mega j contains S2f(j-1), S3f(j-2), S1(j), C1(j+1)
    for (int j = 0; j < 10; ++j){
        const int a_s2 = (j >= 1 && j <= 8), t_s2 = a_s2 ? j - 1 : 0;
        const int a_s3 = (j >= 2),           t_s3 = a_s3 ? j - 2 : 0;
        const int a_s1 = (j <= 7),           t_s1 = a_s1 ? j     : 0;
        const int a_c1 = (j <= 6),           t_c1 = a_c1 ? j + 1 : 0;

        const int e1 = a_s2 ? 512 : 0;
        const int e2 = e1 + (a_s3 ? 1024 : 0);
        const int e3 = e2 + (a_s1 ? 256 : 0);
        const int e4 = e3 + (a_c1 ? 64 : 0);
        if (e4 == 0) continue;

        const ushort* h1p = (t_s1 & 1) ? h1B : h1A;  ushort* h1n = (t_s1 & 1) ? h1A : h1B;
        const ushort* h2p = (t_s2 & 1) ? h2B : h2A;  ushort* h2n = (t_s2 & 1) ? h2A : h2B;
        const ushort* h3p = (t_s3 & 1) ? h3B : h3A;  ushort* h3n = (t_s3 & 1) ? h3A : h3B;

        mega<<<dim3(e4), 256, 0, stream>>>(
            e1, e2, e3,
            t_s2, t_s3, t_s1, t_c1,
            (t_s1 == 0), (t_s2 == 0), (t_s3 == 0),
            xpad, Wxp1, b1, Zx1,
            Whp1, h1p, h1n, c1, g1, be1, mm1, mv1, x2pad,
            Wc2, b2, h2p, h2n, c2, g2, be2, mm2, mv2, x3pad,
            Wc3, b3, h3p, h3n, c3, g3, be3, mm3, mv3, (float*)d_out);
    }
}